// Round 17
// baseline (334.552 us; speedup 1.0000x reference)
//
#include <hip/hip_runtime.h>
#include <math.h>

#define NROWS 500000
#define DIM 256
#define YDIM 50
#define NLAB 1000

#define XT 64
#define NTX ((NROWS + XT - 1) / XT)      // 7813 (last tile: 32 valid rows)
#define XBLOCKS 256
#define ZC 51                            // z' cols: 50 proj + 1 gate-dot

#define YT 128
#define NTY ((NROWS + YT - 1) / YT)      // 3907
#define YBLOCKS 256

typedef __attribute__((ext_vector_type(8))) short frag_ab;
typedef __attribute__((ext_vector_type(4))) float frag_cd;

__device__ __forceinline__ float b2f(unsigned short u) {
    return __uint_as_float(((unsigned)u) << 16);
}
__device__ __forceinline__ unsigned short f2b(float f) {   // RNE f32->bf16
    unsigned u = __float_as_uint(f);
    return (unsigned short)((u + 0x7fffu + ((u >> 16) & 1u)) >> 16);
}
// 1-inst RNE pack: D[15:0]=bf16(lo), D[31:16]=bf16(hi)
__device__ __forceinline__ unsigned cvt_pk_bf16(float lo, float hi) {
    unsigned r;
    asm("v_cvt_pk_bf16_f32 %0, %1, %2" : "=v"(r) : "v"(lo), "v"(hi));
    return r;
}
// LDS-only barrier: does NOT drain vmcnt -> global prefetches stay in flight.
__device__ __forceinline__ void bar_lds() {
    asm volatile("s_waitcnt lgkmcnt(0)\n\ts_barrier" ::: "memory");
}

// ============ x stream: z' = x @ [w2|w1], A-fragments DIRECT from global ====
// No sA staging; 1 barrier/tile (zst+slab double-buffered; scatter(T) overlaps
// phase writes of T+1 into the other buffer). Wave w owns labels (lbl&15)==w.
__global__ __launch_bounds__(1024) void k_xstream(
    const float* __restrict__ x, const int* __restrict__ labels,
    const float* __restrict__ w1, const float* __restrict__ b1,
    const float* __restrict__ w2, unsigned short* __restrict__ zpart,
    float* __restrict__ out)
{
    __shared__ __align__(16) float zst[2][XT][52];              // 26,624 B
    __shared__ __align__(16) unsigned short accz[NLAB * YDIM];  // 100,000 B
    __shared__ int slab[2][XT];                                 //    512 B

    const int tid = threadIdx.x, lane = tid & 63, wib = tid >> 6;
    const int bid = blockIdx.x;
    const int mh = wib >> 2, jt = wib & 3;

    if (bid == 0 && tid == 0) out[0] = 0.0f;
    for (int k = tid; k < NLAB * YDIM / 2; k += 1024)
        reinterpret_cast<unsigned*>(accz)[k] = 0u;

    // B fragments: W' columns = [w2 cols 0..49 | w1 as col 50 | zeros]
    frag_ab bfr[8];
    {
        const int n = 16 * jt + (lane & 15);
        #pragma unroll
        for (int s = 0; s < 8; ++s) {
            const int k0 = 32 * s + (lane >> 4) * 8;
            #pragma unroll
            for (int i = 0; i < 8; ++i) {
                const int kk = k0 + i;
                float v = 0.f;
                if (n < YDIM)       v = w2[kk * YDIM + n];
                else if (n == YDIM) v = w1[kk];
                bfr[s][i] = (short)f2b(v);
            }
        }
    }
    const float b1v = b1[0];
    __syncthreads();                                  // accz zeroed

    // A-fragment address components (same layout the sA path used)
    const int arow = 16 * mh + (lane & 15);           // row within tile, 0..63
    const int kq   = (lane >> 4) * 2;                 // float4 index within 32-elem step

    // load tile t's A-fragments (16 float4 = 8 k-steps x 2) direct from global
    auto PREFA = [&](int t, float4* r) {
        const int rg = t * XT + arow;
        const bool ok = (t < NTX) && (rg < NROWS);
        const float4* base = reinterpret_cast<const float4*>(x) + (size_t)rg * 64;
        #pragma unroll
        for (int s = 0; s < 8; ++s) {
            const int fi = 8 * s + kq;
            r[2 * s]     = ok ? base[fi]     : make_float4(0.f, 0.f, 0.f, 0.f);
            r[2 * s + 1] = ok ? base[fi + 1] : make_float4(0.f, 0.f, 0.f, 0.f);
        }
    };
    auto LLAB = [&](int t) -> int {
        const int rg = t * XT + tid;
        return (tid < XT && rg < NROWS) ? labels[rg] : 0;
    };

    auto process = [&](int pft, float4* r, int& lb, int par) {
        // slab for CURRENT tile (travels with the register set)
        if (tid < XT) slab[par][tid] = lb;

        // ---- MFMA from registers (cvt_pk at use; gate col rides along) ----
        frag_cd c = {0.f, 0.f, 0.f, 0.f};
        #pragma unroll
        for (int s = 0; s < 8; ++s) {
            frag_ab a;
            unsigned* au = reinterpret_cast<unsigned*>(&a);
            au[0] = cvt_pk_bf16(r[2 * s].x,     r[2 * s].y);
            au[1] = cvt_pk_bf16(r[2 * s].z,     r[2 * s].w);
            au[2] = cvt_pk_bf16(r[2 * s + 1].x, r[2 * s + 1].y);
            au[3] = cvt_pk_bf16(r[2 * s + 1].z, r[2 * s + 1].w);
            c = __builtin_amdgcn_mfma_f32_16x16x32_bf16(a, bfr[s], c, 0, 0, 0);
        }

        // prefetch next tile's fragments + labels (hidden under zst/bar/scatter)
        PREFA(pft, r);
        lb = LLAB(pft);

        // ---- stage z'-tile ----
        const int zr = 16 * mh + (lane >> 4) * 4;
        const int zc = 16 * jt + (lane & 15);
        if (zc < ZC) {
            zst[par][zr + 0][zc] = c[0]; zst[par][zr + 1][zc] = c[1];
            zst[par][zr + 2][zc] = c[2]; zst[par][zr + 3][zc] = c[3];
        }
        bar_lds();                     // zst[par] + slab[par] ready

        // ---- gated scatter, pair-packed RMW (lanes 0..24) ----
        {
            const int lbl_lane = slab[par][lane];
            unsigned long long mask = __ballot((lbl_lane & 15) == wib);
            while (mask) {
                const int r2 = __builtin_ctzll(mask);
                mask &= mask - 1;
                const int lbv = __shfl(lbl_lane, r2);
                const float d = zst[par][r2][YDIM];      // gate dot (broadcast)
                const float g = 1.0f / (1.0f + __expf(-(d + b1v)));
                if (lane < 25) {
                    const float2 zv =
                        *reinterpret_cast<const float2*>(&zst[par][r2][2 * lane]);
                    unsigned* ap =
                        reinterpret_cast<unsigned*>(&accz[lbv * YDIM + 2 * lane]);
                    const unsigned old = *ap;
                    const float lo = b2f((unsigned short)(old & 0xffffu)) + g * zv.x;
                    const float hi = b2f((unsigned short)(old >> 16))     + g * zv.y;
                    *ap = cvt_pk_bf16(lo, hi);
                }
            }
        }
        // scatter reads of zst[par] drain at the NEXT tile's bar (lgkmcnt(0))
        // before tile T+2 rewrites zst[par]. No trailing barrier needed.
    };

    float4 r[16];
    PREFA(bid, r);
    int lb = LLAB(bid);
    int par = 0;
    for (int t = bid; t < NTX; t += XBLOCKS) {
        process(t + XBLOCKS, r, lb, par);
        par ^= 1;
    }
    __syncthreads();
    unsigned short* zp = zpart + (size_t)bid * (NLAB * YDIM);
    for (int k = tid; k < NLAB * YDIM; k += 1024) zp[k] = accz[k];
}

// ============ y stream: YT=128 f32 staging (R15 proven form) ============
__global__ __launch_bounds__(1024) void k_ystream(
    const float* __restrict__ y, const int* __restrict__ labels,
    unsigned short* __restrict__ ypart, int* __restrict__ gcnt)
{
    __shared__ __align__(16) unsigned short accy[NLAB * YDIM];  // 100,000 B
    __shared__ __align__(16) float yst[2][YT * YDIM];           //  51,200 B
    __shared__ int slab[2][YT];                                 //   1,024 B
    __shared__ int cnt[NLAB];                                   //   4,000 B

    const int tid = threadIdx.x, lane = tid & 63, wib = tid >> 6;
    const int bid = blockIdx.x;

    for (int k = tid; k < NLAB * YDIM / 2; k += 1024)
        reinterpret_cast<unsigned*>(accy)[k] = 0u;
    for (int k = tid; k < NLAB; k += 1024) cnt[k] = 0;
    __syncthreads();

    auto PREFY = [&](int t, float* v, int& myl) {
        const size_t base = (size_t)t * YT * YDIM;
        const int n = (t < NTY) ? (min(YT, NROWS - t * YT) * YDIM) : 0;
        #pragma unroll
        for (int i = 0; i < 7; ++i) {
            const int k = tid + i * 1024;
            v[i] = (k < n) ? y[base + k] : 0.f;
        }
        const int rg = t * YT + tid;
        myl = (tid < YT && t < NTY && rg < NROWS) ? labels[rg] : -1;
    };

    auto process = [&](int pft, float* v, int& myl, int par) {
        #pragma unroll
        for (int i = 0; i < 7; ++i) {
            const int k = tid + i * 1024;
            if (k < YT * YDIM) yst[par][k] = v[i];
        }
        if (tid < YT) {
            const bool valid = (myl >= 0);
            slab[par][tid] = valid ? myl : 0;
            if (valid) atomicAdd(&cnt[myl], 1);
        }
        PREFY(pft, v, myl);            // depth-2: loads stay in flight
        bar_lds();                     // yst[par] + slab[par] ready

        {
            const int l0 = slab[par][lane];
            const int l1 = slab[par][64 + lane];
            unsigned long long m0 = __ballot((l0 & 15) == wib);
            unsigned long long m1 = __ballot((l1 & 15) == wib);
            while (m0) {
                const int r = __builtin_ctzll(m0); m0 &= m0 - 1;
                const int lb = __shfl(l0, r);
                if (lane < 25) {
                    const float2 yv = *reinterpret_cast<const float2*>(
                        &yst[par][r * YDIM + 2 * lane]);
                    unsigned* ap =
                        reinterpret_cast<unsigned*>(&accy[lb * YDIM + 2 * lane]);
                    const unsigned old = *ap;
                    const float lo = b2f((unsigned short)(old & 0xffffu)) + yv.x;
                    const float hi = b2f((unsigned short)(old >> 16))     + yv.y;
                    *ap = cvt_pk_bf16(lo, hi);
                }
            }
            while (m1) {
                const int r = __builtin_ctzll(m1); m1 &= m1 - 1;
                const int lb = __shfl(l1, r);
                if (lane < 25) {
                    const float2 yv = *reinterpret_cast<const float2*>(
                        &yst[par][(64 + r) * YDIM + 2 * lane]);
                    unsigned* ap =
                        reinterpret_cast<unsigned*>(&accy[lb * YDIM + 2 * lane]);
                    const unsigned old = *ap;
                    const float lo = b2f((unsigned short)(old & 0xffffu)) + yv.x;
                    const float hi = b2f((unsigned short)(old >> 16))     + yv.y;
                    *ap = cvt_pk_bf16(lo, hi);
                }
            }
        }
        // next tile writes yst[par^1]; yst[par] rewrite is >=1 barrier away.
    };

    float vA[7], vB[7];
    int mA, mB;
    PREFY(bid, vA, mA);
    PREFY(bid + YBLOCKS, vB, mB);
    int par = 0;
    for (int t = bid; t < NTY; t += 2 * YBLOCKS) {
        process(t + 2 * YBLOCKS, vA, mA, par); par ^= 1;
        if (t + YBLOCKS < NTY) {
            process(t + 3 * YBLOCKS, vB, mB, par); par ^= 1;
        }
    }
    __syncthreads();
    unsigned short* yp = ypart + (size_t)bid * (NLAB * YDIM);
    for (int k = tid; k < NLAB * YDIM; k += 1024) yp[k] = accy[k];
    for (int k = tid; k < NLAB; k += 1024)
        if (cnt[k]) atomicAdd(&gcnt[k], cnt[k]);
}

// ============ finalize: coalesced partial-reduce + double softmax + loss ===
__global__ __launch_bounds__(256) void k_finalize(
    const unsigned short* __restrict__ zpart,
    const unsigned short* __restrict__ ypart,
    const int* __restrict__ gcnt,
    const float* __restrict__ b2, float* __restrict__ out)
{
    const int tid = threadIdx.x, lane = tid & 63, grp = tid >> 6;
    const int k0 = blockIdx.x * 200;

    float zs = 0.f, ys = 0.f;
    if (tid < 200) {
        const size_t idx = (size_t)k0 + tid;
        #pragma unroll 4
        for (int p = 0; p < XBLOCKS; ++p) {
            zs += b2f(zpart[(size_t)p * (NLAB * YDIM) + idx]);
            ys += b2f(ypart[(size_t)p * (NLAB * YDIM) + idx]);
        }
    }
    __shared__ float zl[200], yl[200];
    if (tid < 200) { zl[tid] = zs; yl[tid] = ys; }
    __syncthreads();

    const int l = blockIdx.x * 4 + grp;
    const bool act = lane < YDIM;
    const float zv = act ? zl[grp * 50 + lane] : 0.f;
    const float yv = act ? yl[grp * 50 + lane] : 0.f;

    const float denom = fmaxf((float)gcnt[l], 1.0f);
    const float NEG = -3.402823466e38f;
    float logit = act ? (zv / denom + b2[lane]) : NEG;
    const float ymean = act ? (yv / denom) : 0.f;

    float m = logit;
    #pragma unroll
    for (int o = 32; o > 0; o >>= 1) m = fmaxf(m, __shfl_xor(m, o));
    float e = act ? __expf(logit - m) : 0.f;
    float s = e;
    #pragma unroll
    for (int o = 32; o > 0; o >>= 1) s += __shfl_xor(s, o);
    const float p = e / s;                 // prediction

    float pm = act ? p : NEG;              // faithful double softmax
    float m2 = pm;
    #pragma unroll
    for (int o = 32; o > 0; o >>= 1) m2 = fmaxf(m2, __shfl_xor(m2, o));
    float e2 = act ? __expf(p - m2) : 0.f;
    float s2 = e2;
    #pragma unroll
    for (int o = 32; o > 0; o >>= 1) s2 += __shfl_xor(s2, o);
    const float logp = p - m2 - __logf(s2);

    float contrib = act ? ymean * logp : 0.f;
    #pragma unroll
    for (int o = 32; o > 0; o >>= 1) contrib += __shfl_xor(contrib, o);
    if (lane == 0) atomicAdd(out, -contrib / (float)NLAB);
}

extern "C" void kernel_launch(void* const* d_in, const int* in_sizes, int n_in,
                              void* d_out, int out_size, void* d_ws, size_t ws_size,
                              hipStream_t stream) {
    const float* x      = (const float*)d_in[0];
    const int*   labels = (const int*)  d_in[1];
    const float* y      = (const float*)d_in[2];
    const float* w1     = (const float*)d_in[3];
    const float* b1     = (const float*)d_in[4];
    const float* w2     = (const float*)d_in[5];
    const float* b2     = (const float*)d_in[6];
    float* out = (float*)d_out;

    // ws: gcnt[1024] ints | zpart[256][50000] bf16 | ypart[256][50000] bf16
    int* gcnt = (int*)d_ws;
    unsigned short* zpart = (unsigned short*)((char*)d_ws + 4096);
    unsigned short* ypart = (unsigned short*)((char*)d_ws + 4096 +
                             (size_t)XBLOCKS * NLAB * YDIM * 2);

    hipMemsetAsync(gcnt, 0, NLAB * sizeof(int), stream);
    k_xstream<<<XBLOCKS, 1024, 0, stream>>>(x, labels, w1, b1, w2, zpart, out);
    k_ystream<<<YBLOCKS, 1024, 0, stream>>>(y, labels, ypart, gcnt);
    k_finalize<<<250, 256, 0, stream>>>(zpart, ypart, gcnt, b2, out);
}

// Round 18
// 282.063 us; speedup vs baseline: 1.1861x; 1.1861x over previous
//
#include <hip/hip_runtime.h>
#include <math.h>

#define NROWS 500000
#define DIM 256
#define YDIM 50
#define NLAB 1000
#define HLAB 500                          // labels per parity half

#define XT 32
#define NTX (NROWS / XT)                  // 15625 exact
#define XBLOCKS 512                       // 2 per CU; pair (2j,2j+1) shares tiles
#define XPAIRS 256
#define ASTRIDE 264                       // bf16 elems per A-tile row (padded)
#define ZC 51                             // z' cols: 50 proj + 1 gate-dot

#define YT 128
#define NTY ((NROWS + YT - 1) / YT)       // 3907
#define YBLOCKS 256

typedef __attribute__((ext_vector_type(8))) short frag_ab;
typedef __attribute__((ext_vector_type(4))) float frag_cd;

__device__ __forceinline__ float b2f(unsigned short u) {
    return __uint_as_float(((unsigned)u) << 16);
}
__device__ __forceinline__ unsigned short f2b(float f) {   // RNE f32->bf16
    unsigned u = __float_as_uint(f);
    return (unsigned short)((u + 0x7fffu + ((u >> 16) & 1u)) >> 16);
}
// 1-inst RNE pack: D[15:0]=bf16(lo), D[31:16]=bf16(hi)
__device__ __forceinline__ unsigned cvt_pk_bf16(float lo, float hi) {
    unsigned r;
    asm("v_cvt_pk_bf16_f32 %0, %1, %2" : "=v"(r) : "v"(lo), "v"(hi));
    return r;
}
// LDS-only barrier: does NOT drain vmcnt -> global prefetches stay in flight.
__device__ __forceinline__ void bar_lds() {
    asm volatile("s_waitcnt lgkmcnt(0)\n\ts_barrier" ::: "memory");
}

// ====== x stream: 512 blocks x 512 thr, 2 blocks/CU, label-parity split =====
// Block b owns labels with (lbl&1)==(b&1); accz[500][50] bf16 (50 KB).
// Pair (2j,2j+1) reads the same tiles (dup reads are L3 hits).
// 2 barriers/tile (R15-proven skeleton); wave w owns ((lbl>>1)&7)==w.
__global__ __launch_bounds__(512, 4) void k_xstream(
    const float* __restrict__ x, const int* __restrict__ labels,
    const float* __restrict__ w1, const float* __restrict__ b1,
    const float* __restrict__ w2, unsigned short* __restrict__ zpart,
    float* __restrict__ out)
{
    __shared__ __align__(16) unsigned short sA[XT * ASTRIDE];   // 16,896 B
    __shared__ __align__(16) float zst[XT][52];                 //  6,656 B
    __shared__ __align__(16) unsigned short accz[HLAB * YDIM];  // 50,000 B
    __shared__ int slab[2][XT];                                 //    256 B

    const int tid = threadIdx.x, lane = tid & 63, wib = tid >> 6;  // 8 waves
    const int bid = blockIdx.x;
    const int p   = bid & 1;            // label parity owned by this block
    const int tb  = bid >> 1;           // shared tile-base of the pair
    const int mh = wib >> 2, jt = wib & 3;                         // mh 0..1

    if (bid == 0 && tid == 0) out[0] = 0.0f;
    for (int k = tid; k < HLAB * YDIM / 2; k += 512)
        reinterpret_cast<unsigned*>(accz)[k] = 0u;

    // B fragments: W' columns = [w2 cols 0..49 | w1 as col 50 | zeros]
    frag_ab bfr[8];
    {
        const int n = 16 * jt + (lane & 15);
        #pragma unroll
        for (int s = 0; s < 8; ++s) {
            const int k0 = 32 * s + (lane >> 4) * 8;
            #pragma unroll
            for (int i = 0; i < 8; ++i) {
                const int kk = k0 + i;
                float v = 0.f;
                if (n < YDIM)       v = w2[kk * YDIM + n];
                else if (n == YDIM) v = w1[kk];
                bfr[s][i] = (short)f2b(v);
            }
        }
    }
    const float b1v = b1[0];
    __syncthreads();                                  // accz zeroed

    auto PREF = [&](int t, float4* r) {
        #pragma unroll
        for (int k = 0; k < 4; ++k) {
            const int rg = t * XT + 4 * wib + k;      // 8 waves x 4 = 32 rows
            r[k] = (t < NTX && rg < NROWS)
                 ? reinterpret_cast<const float4*>(x)[(size_t)rg * 64 + lane]
                 : make_float4(0.f, 0.f, 0.f, 0.f);
        }
    };
    auto LLAB = [&](int t) -> int {
        const int rg = t * XT + tid;
        return (tid < XT && t < NTX && rg < NROWS) ? labels[rg] : -1;
    };

    auto process = [&](int pft, float4* r, int& lb, int par) {
        // ---- phase 0: slab, cvt_pk pack, refill prefetch (depth-2), A-write --
        if (tid < XT) slab[par][tid] = lb;
        uint2 pk[4];
        #pragma unroll
        for (int k = 0; k < 4; ++k) {
            pk[k].x = cvt_pk_bf16(r[k].x, r[k].y);
            pk[k].y = cvt_pk_bf16(r[k].z, r[k].w);
        }
        PREF(pft, r);                  // loads stay in flight across barriers
        lb = LLAB(pft);                // labels travel with this reg set
        const int row = 4 * wib;
        #pragma unroll
        for (int k = 0; k < 4; ++k)
            *reinterpret_cast<uint2*>(&sA[(row + k) * ASTRIDE + lane * 4]) = pk[k];
        bar_lds();                     // bar1: sA + slab[par] ready

        // ---- phase 1: MFMA (gate col rides along), stage z'-tile ----
        frag_cd c = {0.f, 0.f, 0.f, 0.f};
        #pragma unroll
        for (int s = 0; s < 8; ++s) {
            frag_ab a = *reinterpret_cast<const frag_ab*>(
                &sA[(16 * mh + (lane & 15)) * ASTRIDE + 32 * s + (lane >> 4) * 8]);
            c = __builtin_amdgcn_mfma_f32_16x16x32_bf16(a, bfr[s], c, 0, 0, 0);
        }
        const int zr = 16 * mh + (lane >> 4) * 4;
        const int zc = 16 * jt + (lane & 15);
        if (zc < ZC) {
            zst[zr + 0][zc] = c[0]; zst[zr + 1][zc] = c[1];
            zst[zr + 2][zc] = c[2]; zst[zr + 3][zc] = c[3];
        }
        bar_lds();                     // bar2: zst ready

        // ---- phase 2: gated scatter; own (lbl&1)==p && ((lbl>>1)&7)==wib ----
        {
            const int lbl_lane = slab[par][lane & 31];
            const bool own = (lane < 32) && (lbl_lane >= 0) &&
                             ((lbl_lane & 1) == p) &&
                             (((lbl_lane >> 1) & 7) == wib);
            unsigned long long mask = __ballot(own);
            while (mask) {
                const int r2 = __builtin_ctzll(mask);
                mask &= mask - 1;
                const int lbv = __shfl(lbl_lane, r2);
                const float d = zst[r2][YDIM];           // gate dot (broadcast)
                const float g = 1.0f / (1.0f + __expf(-(d + b1v)));
                if (lane < 25) {
                    const float2 zv =
                        *reinterpret_cast<const float2*>(&zst[r2][2 * lane]);
                    unsigned* ap = reinterpret_cast<unsigned*>(
                        &accz[(lbv >> 1) * YDIM + 2 * lane]);
                    const unsigned old = *ap;
                    const float lo = b2f((unsigned short)(old & 0xffffu)) + g * zv.x;
                    const float hi = b2f((unsigned short)(old >> 16))     + g * zv.y;
                    *ap = cvt_pk_bf16(lo, hi);
                }
            }
        }
        // zst/slab reuse protected by next tile's bar1 (lgkmcnt(0) drains reads)
    };

    float4 rA[4], rB[4];
    PREF(tb, rA);
    PREF(tb + XPAIRS, rB);
    int lbA = LLAB(tb), lbB = LLAB(tb + XPAIRS);
    int par = 0;
    for (int t = tb; t < NTX; t += 2 * XPAIRS) {
        process(t + 2 * XPAIRS, rA, lbA, par); par ^= 1;
        if (t + XPAIRS < NTX) {
            process(t + 3 * XPAIRS, rB, lbB, par); par ^= 1;
        }
    }
    __syncthreads();
    unsigned short* zp = zpart + (size_t)bid * (HLAB * YDIM);
    for (int k = tid; k < HLAB * YDIM; k += 512) zp[k] = accz[k];
}

// ============ y stream: R15 proven form (unchanged) ============
__global__ __launch_bounds__(1024) void k_ystream(
    const float* __restrict__ y, const int* __restrict__ labels,
    unsigned short* __restrict__ ypart, int* __restrict__ gcnt)
{
    __shared__ __align__(16) unsigned short accy[NLAB * YDIM];  // 100,000 B
    __shared__ __align__(16) float yst[2][YT * YDIM];           //  51,200 B
    __shared__ int slab[2][YT];                                 //   1,024 B
    __shared__ int cnt[NLAB];                                   //   4,000 B

    const int tid = threadIdx.x, lane = tid & 63, wib = tid >> 6;
    const int bid = blockIdx.x;

    for (int k = tid; k < NLAB * YDIM / 2; k += 1024)
        reinterpret_cast<unsigned*>(accy)[k] = 0u;
    for (int k = tid; k < NLAB; k += 1024) cnt[k] = 0;
    __syncthreads();

    auto PREFY = [&](int t, float* v, int& myl) {
        const size_t base = (size_t)t * YT * YDIM;
        const int n = (t < NTY) ? (min(YT, NROWS - t * YT) * YDIM) : 0;
        #pragma unroll
        for (int i = 0; i < 7; ++i) {
            const int k = tid + i * 1024;
            v[i] = (k < n) ? y[base + k] : 0.f;
        }
        const int rg = t * YT + tid;
        myl = (tid < YT && t < NTY && rg < NROWS) ? labels[rg] : -1;
    };

    auto process = [&](int pft, float* v, int& myl, int par) {
        #pragma unroll
        for (int i = 0; i < 7; ++i) {
            const int k = tid + i * 1024;
            if (k < YT * YDIM) yst[par][k] = v[i];
        }
        if (tid < YT) {
            const bool valid = (myl >= 0);
            slab[par][tid] = valid ? myl : 0;
            if (valid) atomicAdd(&cnt[myl], 1);
        }
        PREFY(pft, v, myl);            // depth-2: loads stay in flight
        bar_lds();                     // yst[par] + slab[par] ready

        {
            const int l0 = slab[par][lane];
            const int l1 = slab[par][64 + lane];
            unsigned long long m0 = __ballot((l0 & 15) == wib);
            unsigned long long m1 = __ballot((l1 & 15) == wib);
            while (m0) {
                const int r = __builtin_ctzll(m0); m0 &= m0 - 1;
                const int lb = __shfl(l0, r);
                if (lane < 25) {
                    const float2 yv = *reinterpret_cast<const float2*>(
                        &yst[par][r * YDIM + 2 * lane]);
                    unsigned* ap =
                        reinterpret_cast<unsigned*>(&accy[lb * YDIM + 2 * lane]);
                    const unsigned old = *ap;
                    const float lo = b2f((unsigned short)(old & 0xffffu)) + yv.x;
                    const float hi = b2f((unsigned short)(old >> 16))     + yv.y;
                    *ap = cvt_pk_bf16(lo, hi);
                }
            }
            while (m1) {
                const int r = __builtin_ctzll(m1); m1 &= m1 - 1;
                const int lb = __shfl(l1, r);
                if (lane < 25) {
                    const float2 yv = *reinterpret_cast<const float2*>(
                        &yst[par][(64 + r) * YDIM + 2 * lane]);
                    unsigned* ap =
                        reinterpret_cast<unsigned*>(&accy[lb * YDIM + 2 * lane]);
                    const unsigned old = *ap;
                    const float lo = b2f((unsigned short)(old & 0xffffu)) + yv.x;
                    const float hi = b2f((unsigned short)(old >> 16))     + yv.y;
                    *ap = cvt_pk_bf16(lo, hi);
                }
            }
        }
        // next tile writes yst[par^1]; yst[par] rewrite is >=1 barrier away.
    };

    float vA[7], vB[7];
    int mA, mB;
    PREFY(bid, vA, mA);
    PREFY(bid + YBLOCKS, vB, mB);
    int par = 0;
    for (int t = bid; t < NTY; t += 2 * YBLOCKS) {
        process(t + 2 * YBLOCKS, vA, mA, par); par ^= 1;
        if (t + YBLOCKS < NTY) {
            process(t + 3 * YBLOCKS, vB, mB, par); par ^= 1;
        }
    }
    __syncthreads();
    unsigned short* yp = ypart + (size_t)bid * (NLAB * YDIM);
    for (int k = tid; k < NLAB * YDIM; k += 1024) yp[k] = accy[k];
    for (int k = tid; k < NLAB; k += 1024)
        if (cnt[k]) atomicAdd(&gcnt[k], cnt[k]);
}

// ====== finalize: parity-split zpart reduce + double softmax + loss =========
__global__ __launch_bounds__(256) void k_finalize(
    const unsigned short* __restrict__ zpart,
    const unsigned short* __restrict__ ypart,
    const int* __restrict__ gcnt,
    const float* __restrict__ b2, float* __restrict__ out)
{
    const int tid = threadIdx.x, lane = tid & 63, grp = tid >> 6;
    const int k0 = blockIdx.x * 200;    // flat (l*50+c) positions

    float zs = 0.f, ys = 0.f;
    if (tid < 200) {
        const int flat = k0 + tid;
        const int l = flat / 50, c = flat - 50 * l;
        const int pp = l & 1;
        const size_t zidx = (size_t)(l >> 1) * YDIM + c;
        #pragma unroll 4
        for (int j = 0; j < XPAIRS; ++j)
            zs += b2f(zpart[(size_t)(2 * j + pp) * (HLAB * YDIM) + zidx]);
        #pragma unroll 4
        for (int pb = 0; pb < YBLOCKS; ++pb)
            ys += b2f(ypart[(size_t)pb * (NLAB * YDIM) + flat]);
    }
    __shared__ float zl[200], yl[200];
    if (tid < 200) { zl[tid] = zs; yl[tid] = ys; }
    __syncthreads();

    const int l = blockIdx.x * 4 + grp;
    const bool act = lane < YDIM;
    const float zv = act ? zl[grp * 50 + lane] : 0.f;
    const float yv = act ? yl[grp * 50 + lane] : 0.f;

    const float denom = fmaxf((float)gcnt[l], 1.0f);
    const float NEG = -3.402823466e38f;
    float logit = act ? (zv / denom + b2[lane]) : NEG;
    const float ymean = act ? (yv / denom) : 0.f;

    float m = logit;
    #pragma unroll
    for (int o = 32; o > 0; o >>= 1) m = fmaxf(m, __shfl_xor(m, o));
    float e = act ? __expf(logit - m) : 0.f;
    float s = e;
    #pragma unroll
    for (int o = 32; o > 0; o >>= 1) s += __shfl_xor(s, o);
    const float p = e / s;                 // prediction

    float pm = act ? p : NEG;              // faithful double softmax
    float m2 = pm;
    #pragma unroll
    for (int o = 32; o > 0; o >>= 1) m2 = fmaxf(m2, __shfl_xor(m2, o));
    float e2 = act ? __expf(p - m2) : 0.f;
    float s2 = e2;
    #pragma unroll
    for (int o = 32; o > 0; o >>= 1) s2 += __shfl_xor(s2, o);
    const float logp = p - m2 - __logf(s2);

    float contrib = act ? ymean * logp : 0.f;
    #pragma unroll
    for (int o = 32; o > 0; o >>= 1) contrib += __shfl_xor(contrib, o);
    if (lane == 0) atomicAdd(out, -contrib / (float)NLAB);
}

extern "C" void kernel_launch(void* const* d_in, const int* in_sizes, int n_in,
                              void* d_out, int out_size, void* d_ws, size_t ws_size,
                              hipStream_t stream) {
    const float* x      = (const float*)d_in[0];
    const int*   labels = (const int*)  d_in[1];
    const float* y      = (const float*)d_in[2];
    const float* w1     = (const float*)d_in[3];
    const float* b1     = (const float*)d_in[4];
    const float* w2     = (const float*)d_in[5];
    const float* b2     = (const float*)d_in[6];
    float* out = (float*)d_out;

    // ws: gcnt[1024] ints | zpart[512][25000] bf16 | ypart[256][50000] bf16
    int* gcnt = (int*)d_ws;
    unsigned short* zpart = (unsigned short*)((char*)d_ws + 4096);
    unsigned short* ypart = (unsigned short*)((char*)d_ws + 4096 +
                             (size_t)XBLOCKS * HLAB * YDIM * 2);

    hipMemsetAsync(gcnt, 0, NLAB * sizeof(int), stream);
    k_xstream<<<XBLOCKS, 512, 0, stream>>>(x, labels, w1, b1, w2, zpart, out);
    k_ystream<<<YBLOCKS, 1024, 0, stream>>>(y, labels, ypart, gcnt);
    k_finalize<<<250, 256, 0, stream>>>(zpart, ypart, gcnt, b2, out);
}

// Round 19
// 224.887 us; speedup vs baseline: 1.4876x; 1.2542x over previous
//
#include <hip/hip_runtime.h>
#include <math.h>

#define NROWS 500000
#define DIM 256
#define YDIM 50
#define NLAB 1000
#define HLAB 500

#define CHK 2048
#define NCH ((NROWS + CHK - 1) / CHK)     // 245

#define XT 32
#define XBLOCKS 512                       // 2 per CU
#define XPAIRS 256
#define ASTRIDE 264
#define ZC 51

#define YT 128
#define NTY ((NROWS + YT - 1) / YT)       // 3907
#define YBLOCKS 256

typedef __attribute__((ext_vector_type(8))) short frag_ab;
typedef __attribute__((ext_vector_type(4))) float frag_cd;

__device__ __forceinline__ float b2f(unsigned short u) {
    return __uint_as_float(((unsigned)u) << 16);
}
__device__ __forceinline__ unsigned short f2b(float f) {
    unsigned u = __float_as_uint(f);
    return (unsigned short)((u + 0x7fffu + ((u >> 16) & 1u)) >> 16);
}
__device__ __forceinline__ unsigned cvt_pk_bf16(float lo, float hi) {
    unsigned r;
    asm("v_cvt_pk_bf16_f32 %0, %1, %2" : "=v"(r) : "v"(lo), "v"(hi));
    return r;
}
__device__ __forceinline__ void bar_lds() {
    asm volatile("s_waitcnt lgkmcnt(0)\n\ts_barrier" ::: "memory");
}

// ====== pre-pass 1: per-chunk parity-0 counts ======
__global__ __launch_bounds__(256) void k_cnt(const int* __restrict__ labels,
                                             int* __restrict__ cnt0) {
    const int c = blockIdx.x, base = c * CHK;
    const int n = min(CHK, NROWS - base);
    __shared__ int sc;
    if (threadIdx.x == 0) sc = 0;
    __syncthreads();
    int k0 = 0;
    for (int i = threadIdx.x; i < n; i += 256) k0 += ((labels[base + i] & 1) == 0);
    #pragma unroll
    for (int o = 32; o > 0; o >>= 1) k0 += __shfl_xor(k0, o);
    if ((threadIdx.x & 63) == 0) atomicAdd(&sc, k0);
    __syncthreads();
    if (threadIdx.x == 0) cnt0[c] = sc;
}

// ====== pre-pass 2: scan (245 bins), total0, zero out ======
__global__ __launch_bounds__(256) void k_scan(const int* __restrict__ cnt0,
                                              int* __restrict__ off0,
                                              int* __restrict__ n0buf,
                                              float* __restrict__ out) {
    __shared__ int tmp[256];
    const int t = threadIdx.x;
    const int v = (t < NCH) ? cnt0[t] : 0;
    tmp[t] = v;
    __syncthreads();
    for (int o = 1; o < 256; o <<= 1) {
        const int a = (t >= o) ? tmp[t - o] : 0;
        __syncthreads();
        tmp[t] += a;
        __syncthreads();
    }
    if (t < NCH) off0[t] = tmp[t] - v;
    if (t == NCH - 1) n0buf[0] = tmp[t];
    if (t == 0) out[0] = 0.0f;
}

// ====== pre-pass 3: deterministic ordered parity scatter ======
__global__ __launch_bounds__(256) void k_order(const int* __restrict__ labels,
                                               const int* __restrict__ off0,
                                               const int* __restrict__ n0buf,
                                               int* __restrict__ plist) {
    const int c = blockIdx.x, t = threadIdx.x;
    const int base = c * CHK;
    const int n = min(CHK, NROWS - base);
    int lb[8];
    int k0 = 0, k1 = 0;
    #pragma unroll
    for (int i = 0; i < 8; ++i) {
        const int r = t * 8 + i;
        lb[i] = (r < n) ? labels[base + r] : -1;
        if (lb[i] >= 0) { if (lb[i] & 1) ++k1; else ++k0; }
    }
    __shared__ int s0[256], s1[256];
    s0[t] = k0; s1[t] = k1;
    __syncthreads();
    for (int o = 1; o < 256; o <<= 1) {
        const int a0 = (t >= o) ? s0[t - o] : 0;
        const int a1 = (t >= o) ? s1[t - o] : 0;
        __syncthreads();
        s0[t] += a0; s1[t] += a1;
        __syncthreads();
    }
    int w0 = off0[c] + (s0[t] - k0);
    int w1 = n0buf[0] + base - off0[c] + (s1[t] - k1);
    #pragma unroll
    for (int i = 0; i < 8; ++i) {
        if (lb[i] >= 0) {
            const int r = base + t * 8 + i;
            if (lb[i] & 1) plist[w1++] = r; else plist[w0++] = r;
        }
    }
}

// ====== x stream: 512 blocks (2/CU), parity-partitioned rows via plist ======
__global__ __launch_bounds__(512, 4) void k_xstream(
    const float* __restrict__ x, const int* __restrict__ labels,
    const int* __restrict__ plist, const int* __restrict__ n0buf,
    const float* __restrict__ w1, const float* __restrict__ b1,
    const float* __restrict__ w2, unsigned short* __restrict__ zpart)
{
    __shared__ __align__(16) unsigned short sA[XT * ASTRIDE];   // 16,896 B
    __shared__ __align__(16) float zst[XT][52];                 //  6,656 B
    __shared__ __align__(16) unsigned short accz[HLAB * YDIM];  // 50,000 B
    __shared__ int slab[2][XT];                                 //    256 B

    const int tid = threadIdx.x, lane = tid & 63, wib = tid >> 6;  // 8 waves
    const int bid = blockIdx.x;
    const int p = bid & 1, j = bid >> 1;
    const int mh = wib >> 2, jt = wib & 3;

    for (int k = tid; k < HLAB * YDIM / 2; k += 512)
        reinterpret_cast<unsigned*>(accz)[k] = 0u;

    frag_ab bfr[8];
    {
        const int n = 16 * jt + (lane & 15);
        #pragma unroll
        for (int s = 0; s < 8; ++s) {
            const int k0 = 32 * s + (lane >> 4) * 8;
            #pragma unroll
            for (int i = 0; i < 8; ++i) {
                const int kk = k0 + i;
                float v = 0.f;
                if (n < YDIM)       v = w2[kk * YDIM + n];
                else if (n == YDIM) v = w1[kk];
                bfr[s][i] = (short)f2b(v);
            }
        }
    }
    const float b1v = b1[0];
    const int n0 = n0buf[0];
    const int np = p ? (NROWS - n0) : n0;
    const int base = p ? n0 : 0;
    const int ntp = (np + XT - 1) / XT;
    __syncthreads();                                  // accz zeroed

    // per-wave row indices (4) for tile t
    auto LIDX = [&](int t, int* idx) {
        #pragma unroll
        for (int k = 0; k < 4; ++k) {
            const int li = t * XT + 4 * wib + k;
            idx[k] = (t < ntp && li < np) ? plist[base + li] : -1;
        }
    };
    // per-thread (tid<XT) plist entry for tile t (label lookup)
    auto LPL = [&](int t) -> int {
        const int li = t * XT + tid;
        return (tid < XT && t < ntp && li < np) ? plist[base + li] : -1;
    };
    auto PREF = [&](const int* idx, float4* r) {
        #pragma unroll
        for (int k = 0; k < 4; ++k)
            r[k] = (idx[k] >= 0)
                 ? reinterpret_cast<const float4*>(x)[(size_t)idx[k] * 64 + lane]
                 : make_float4(0.f, 0.f, 0.f, 0.f);
    };

    // process tile T (regs r/lb); rows+labels of T+512 prefetched via nidx/npl;
    // then reload nidx/npl for T+1024.
    auto process = [&](int tnn, float4* r, int& lb, int* nidx, int& npl, int par) {
        if (tid < XT) slab[par][tid] = lb;
        uint2 pk[4];
        #pragma unroll
        for (int k = 0; k < 4; ++k) {
            pk[k].x = cvt_pk_bf16(r[k].x, r[k].y);
            pk[k].y = cvt_pk_bf16(r[k].z, r[k].w);
        }
        PREF(nidx, r);                 // rows of T+512 (addresses ready)
        lb = (npl >= 0) ? labels[npl] : -1;   // labels of T+512 (address ready)
        LIDX(tnn, nidx);               // indices of T+1024
        npl = LPL(tnn);
        const int row = 4 * wib;
        #pragma unroll
        for (int k = 0; k < 4; ++k)
            *reinterpret_cast<uint2*>(&sA[(row + k) * ASTRIDE + lane * 4]) = pk[k];
        bar_lds();                     // bar1: sA + slab[par] ready

        frag_cd c = {0.f, 0.f, 0.f, 0.f};
        #pragma unroll
        for (int s = 0; s < 8; ++s) {
            frag_ab a = *reinterpret_cast<const frag_ab*>(
                &sA[(16 * mh + (lane & 15)) * ASTRIDE + 32 * s + (lane >> 4) * 8]);
            c = __builtin_amdgcn_mfma_f32_16x16x32_bf16(a, bfr[s], c, 0, 0, 0);
        }
        const int zr = 16 * mh + (lane >> 4) * 4;
        const int zc = 16 * jt + (lane & 15);
        if (zc < ZC) {
            zst[zr + 0][zc] = c[0]; zst[zr + 1][zc] = c[1];
            zst[zr + 2][zc] = c[2]; zst[zr + 3][zc] = c[3];
        }
        bar_lds();                     // bar2: zst ready

        {
            const int lbl_lane = slab[par][lane & 31];
            const bool own = (lane < 32) && (lbl_lane >= 0) &&
                             (((lbl_lane >> 1) & 7) == wib);
            unsigned long long mask = __ballot(own);
            while (mask) {
                const int r2 = __builtin_ctzll(mask);
                mask &= mask - 1;
                const int lbv = __shfl(lbl_lane, r2);
                const float d = zst[r2][YDIM];
                const float g = 1.0f / (1.0f + __expf(-(d + b1v)));
                if (lane < 25) {
                    const float2 zv =
                        *reinterpret_cast<const float2*>(&zst[r2][2 * lane]);
                    unsigned* ap = reinterpret_cast<unsigned*>(
                        &accz[(lbv >> 1) * YDIM + 2 * lane]);
                    const unsigned old = *ap;
                    const float lo = b2f((unsigned short)(old & 0xffffu)) + g * zv.x;
                    const float hi = b2f((unsigned short)(old >> 16))     + g * zv.y;
                    *ap = cvt_pk_bf16(lo, hi);
                }
            }
        }
        // zst/slab reuse protected by next tile's bar1 (lgkmcnt(0))
    };

    // init pipeline: sets A (tiles j, j+512, ...) and B (j+256, j+768, ...)
    float4 rA[4], rB[4];
    int idxA[4], idxB[4], nidxA[4], nidxB[4];
    int lbA, lbB, nplA, nplB;
    LIDX(j, idxA);            PREF(idxA, rA);
    { const int pl = LPL(j);            lbA = (pl >= 0) ? labels[pl] : -1; }
    LIDX(j + XPAIRS, idxB);   PREF(idxB, rB);
    { const int pl = LPL(j + XPAIRS);   lbB = (pl >= 0) ? labels[pl] : -1; }
    LIDX(j + 2 * XPAIRS, nidxA);  nplA = LPL(j + 2 * XPAIRS);
    LIDX(j + 3 * XPAIRS, nidxB);  nplB = LPL(j + 3 * XPAIRS);

    int par = 0;
    for (int t = j; t < ntp; t += 2 * XPAIRS) {
        process(t + 4 * XPAIRS, rA, lbA, nidxA, nplA, par); par ^= 1;
        if (t + XPAIRS < ntp) {
            process(t + 5 * XPAIRS, rB, lbB, nidxB, nplB, par); par ^= 1;
        }
    }
    __syncthreads();
    unsigned short* zp = zpart + (size_t)bid * (HLAB * YDIM);
    for (int k = tid; k < HLAB * YDIM; k += 512) zp[k] = accz[k];
}

// ============ y stream: R15 proven form ============
__global__ __launch_bounds__(1024) void k_ystream(
    const float* __restrict__ y, const int* __restrict__ labels,
    unsigned short* __restrict__ ypart, int* __restrict__ gcnt)
{
    __shared__ __align__(16) unsigned short accy[NLAB * YDIM];
    __shared__ __align__(16) float yst[2][YT * YDIM];
    __shared__ int slab[2][YT];
    __shared__ int cnt[NLAB];

    const int tid = threadIdx.x, lane = tid & 63, wib = tid >> 6;
    const int bid = blockIdx.x;

    for (int k = tid; k < NLAB * YDIM / 2; k += 1024)
        reinterpret_cast<unsigned*>(accy)[k] = 0u;
    for (int k = tid; k < NLAB; k += 1024) cnt[k] = 0;
    __syncthreads();

    auto PREFY = [&](int t, float* v, int& myl) {
        const size_t base = (size_t)t * YT * YDIM;
        const int n = (t < NTY) ? (min(YT, NROWS - t * YT) * YDIM) : 0;
        #pragma unroll
        for (int i = 0; i < 7; ++i) {
            const int k = tid + i * 1024;
            v[i] = (k < n) ? y[base + k] : 0.f;
        }
        const int rg = t * YT + tid;
        myl = (tid < YT && t < NTY && rg < NROWS) ? labels[rg] : -1;
    };

    auto process = [&](int pft, float* v, int& myl, int par) {
        #pragma unroll
        for (int i = 0; i < 7; ++i) {
            const int k = tid + i * 1024;
            if (k < YT * YDIM) yst[par][k] = v[i];
        }
        if (tid < YT) {
            const bool valid = (myl >= 0);
            slab[par][tid] = valid ? myl : 0;
            if (valid) atomicAdd(&cnt[myl], 1);
        }
        PREFY(pft, v, myl);
        bar_lds();

        {
            const int l0 = slab[par][lane];
            const int l1 = slab[par][64 + lane];
            unsigned long long m0 = __ballot((l0 & 15) == wib);
            unsigned long long m1 = __ballot((l1 & 15) == wib);
            while (m0) {
                const int r = __builtin_ctzll(m0); m0 &= m0 - 1;
                const int lb = __shfl(l0, r);
                if (lane < 25) {
                    const float2 yv = *reinterpret_cast<const float2*>(
                        &yst[par][r * YDIM + 2 * lane]);
                    unsigned* ap =
                        reinterpret_cast<unsigned*>(&accy[lb * YDIM + 2 * lane]);
                    const unsigned old = *ap;
                    const float lo = b2f((unsigned short)(old & 0xffffu)) + yv.x;
                    const float hi = b2f((unsigned short)(old >> 16))     + yv.y;
                    *ap = cvt_pk_bf16(lo, hi);
                }
            }
            while (m1) {
                const int r = __builtin_ctzll(m1); m1 &= m1 - 1;
                const int lb = __shfl(l1, r);
                if (lane < 25) {
                    const float2 yv = *reinterpret_cast<const float2*>(
                        &yst[par][(64 + r) * YDIM + 2 * lane]);
                    unsigned* ap =
                        reinterpret_cast<unsigned*>(&accy[lb * YDIM + 2 * lane]);
                    const unsigned old = *ap;
                    const float lo = b2f((unsigned short)(old & 0xffffu)) + yv.x;
                    const float hi = b2f((unsigned short)(old >> 16))     + yv.y;
                    *ap = cvt_pk_bf16(lo, hi);
                }
            }
        }
    };

    float vA[7], vB[7];
    int mA, mB;
    PREFY(bid, vA, mA);
    PREFY(bid + YBLOCKS, vB, mB);
    int par = 0;
    for (int t = bid; t < NTY; t += 2 * YBLOCKS) {
        process(t + 2 * YBLOCKS, vA, mA, par); par ^= 1;
        if (t + YBLOCKS < NTY) {
            process(t + 3 * YBLOCKS, vB, mB, par); par ^= 1;
        }
    }
    __syncthreads();
    unsigned short* yp = ypart + (size_t)bid * (NLAB * YDIM);
    for (int k = tid; k < NLAB * YDIM; k += 1024) yp[k] = accy[k];
    for (int k = tid; k < NLAB; k += 1024)
        if (cnt[k]) atomicAdd(&gcnt[k], cnt[k]);
}

// ====== finalize: parity-split zpart reduce + double softmax + loss ======
__global__ __launch_bounds__(256) void k_finalize(
    const unsigned short* __restrict__ zpart,
    const unsigned short* __restrict__ ypart,
    const int* __restrict__ gcnt,
    const float* __restrict__ b2, float* __restrict__ out)
{
    const int tid = threadIdx.x, lane = tid & 63, grp = tid >> 6;
    const int k0 = blockIdx.x * 200;

    float zs = 0.f, ys = 0.f;
    if (tid < 200) {
        const int flat = k0 + tid;
        const int l = flat / 50, c = flat - 50 * l;
        const int pp = l & 1;
        const size_t zidx = (size_t)(l >> 1) * YDIM + c;
        #pragma unroll 4
        for (int j = 0; j < XPAIRS; ++j)
            zs += b2f(zpart[(size_t)(2 * j + pp) * (HLAB * YDIM) + zidx]);
        #pragma unroll 4
        for (int pb = 0; pb < YBLOCKS; ++pb)
            ys += b2f(ypart[(size_t)pb * (NLAB * YDIM) + flat]);
    }
    __shared__ float zl[200], yl[200];
    if (tid < 200) { zl[tid] = zs; yl[tid] = ys; }
    __syncthreads();

    const int l = blockIdx.x * 4 + grp;
    const bool act = lane < YDIM;
    const float zv = act ? zl[grp * 50 + lane] : 0.f;
    const float yv = act ? yl[grp * 50 + lane] : 0.f;

    const float denom = fmaxf((float)gcnt[l], 1.0f);
    const float NEG = -3.402823466e38f;
    float logit = act ? (zv / denom + b2[lane]) : NEG;
    const float ymean = act ? (yv / denom) : 0.f;

    float m = logit;
    #pragma unroll
    for (int o = 32; o > 0; o >>= 1) m = fmaxf(m, __shfl_xor(m, o));
    float e = act ? __expf(logit - m) : 0.f;
    float s = e;
    #pragma unroll
    for (int o = 32; o > 0; o >>= 1) s += __shfl_xor(s, o);
    const float p = e / s;

    float pm = act ? p : NEG;
    float m2 = pm;
    #pragma unroll
    for (int o = 32; o > 0; o >>= 1) m2 = fmaxf(m2, __shfl_xor(m2, o));
    float e2 = act ? __expf(p - m2) : 0.f;
    float s2 = e2;
    #pragma unroll
    for (int o = 32; o > 0; o >>= 1) s2 += __shfl_xor(s2, o);
    const float logp = p - m2 - __logf(s2);

    float contrib = act ? ymean * logp : 0.f;
    #pragma unroll
    for (int o = 32; o > 0; o >>= 1) contrib += __shfl_xor(contrib, o);
    if (lane == 0) atomicAdd(out, -contrib / (float)NLAB);
}

extern "C" void kernel_launch(void* const* d_in, const int* in_sizes, int n_in,
                              void* d_out, int out_size, void* d_ws, size_t ws_size,
                              hipStream_t stream) {
    const float* x      = (const float*)d_in[0];
    const int*   labels = (const int*)  d_in[1];
    const float* y      = (const float*)d_in[2];
    const float* w1     = (const float*)d_in[3];
    const float* b1     = (const float*)d_in[4];
    const float* w2     = (const float*)d_in[5];
    const float* b2     = (const float*)d_in[6];
    float* out = (float*)d_out;

    // ws: gcnt[1024] | cnt0[256] | off0[256] | n0buf[16] | plist[500000]
    //     | zpart[512][25000] bf16 | ypart[256][50000] bf16
    char* w = (char*)d_ws;
    int* gcnt  = (int*)w;
    int* cnt0  = (int*)(w + 4096);
    int* off0  = (int*)(w + 5120);
    int* n0buf = (int*)(w + 6144);
    int* plist = (int*)(w + 8192);
    unsigned short* zpart = (unsigned short*)(w + 8192 + (size_t)NROWS * 4);
    unsigned short* ypart = (unsigned short*)((char*)zpart +
                             (size_t)XBLOCKS * HLAB * YDIM * 2);

    hipMemsetAsync(gcnt, 0, NLAB * sizeof(int), stream);
    k_cnt<<<NCH, 256, 0, stream>>>(labels, cnt0);
    k_scan<<<1, 256, 0, stream>>>(cnt0, off0, n0buf, out);
    k_order<<<NCH, 256, 0, stream>>>(labels, off0, n0buf, plist);
    k_xstream<<<XBLOCKS, 512, 0, stream>>>(x, labels, plist, n0buf,
                                           w1, b1, w2, zpart);
    k_ystream<<<YBLOCKS, 1024, 0, stream>>>(y, labels, ypart, gcnt);
    k_finalize<<<250, 256, 0, stream>>>(zpart, ypart, gcnt, b2, out);
}